// Round 5
// baseline (1256.601 us; speedup 1.0000x reference)
//
#include <hip/hip_runtime.h>
#include <hip/hip_bf16.h>

#define NN      2048
#define NSTEPS  2047
#define NPAIRS  1024
#define MROWS   8192

typedef __attribute__((ext_vector_type(8))) __bf16 bf16x8;
typedef __attribute__((ext_vector_type(4))) float  f32x4;
typedef __attribute__((ext_vector_type(2))) float  f32x2;

__device__ __forceinline__ unsigned short f2bf(float f) {
  unsigned int u = __float_as_uint(f);
  u += 0x7fffu + ((u >> 16) & 1u);   // RNE
  return (unsigned short)(u >> 16);
}

__device__ __forceinline__ void gload_lds16(const void* g, void* l) {
  __builtin_amdgcn_global_load_lds((const __attribute__((address_space(1))) void*)g,
                                   (__attribute__((address_space(3))) void*)l, 16, 0, 0);
}

// ---- kernel 1: angles -> (cos,sin) table, layout cs[step][pair] (8 KB/step slice)
__global__ __launch_bounds__(256) void prep_kernel(
    const float* __restrict__ angles, float2* __restrict__ cs) {
  int idx = blockIdx.x * 256 + threadIdx.x;
  if (idx >= NSTEPS * NPAIRS) return;
  float s, c;
  sincosf(angles[idx], &s, &c);
  cs[idx] = make_float2(c, s);
}

// ---- kernel 2: x fp32 -> bf16 (vectorized)
__global__ __launch_bounds__(256) void cvt_kernel(
    const float4* __restrict__ x, ushort4* __restrict__ xb, int n4) {
  int idx = blockIdx.x * 256 + threadIdx.x;
  if (idx >= n4) return;
  float4 v = x[idx];
  ushort4 o;
  o.x = f2bf(v.x); o.y = f2bf(v.y); o.z = f2bf(v.z); o.w = f2bf(v.w);
  xb[idx] = o;
}

// ---- kernel 3: register-systolic build of U (position space, static pairing).
// WG = 8 waves (512 thr) = (q = pair-quarter, wv&3) x (g = row-group, wv>>2).
// Row-group g owns rows {bid*4+2g, bid*4+2g+1} as one f32x2; lane of quarter q owns
// pairs 256q+4l+e (e=0..3). cs slice staged ONCE per WG (1KB per wave per step),
// quad-buffered LDS, counted vmcnt(2) + raw s_barrier (loads in flight across barriers).
// 512 WGs -> 2 WG/CU, 16 waves/CU, 4 waves/SIMD.
__global__ __launch_bounds__(512, 4) void build_kernel(
    const char* __restrict__ csb, unsigned short* __restrict__ Ub) {
  __shared__ __align__(16) char lds_cs[4][8192];
  __shared__ f32x2 exch[2][2][2][3];   // [parity][g][0=F fwd,1=S bwd][slot]

  const int tid  = threadIdx.x;
  const int lane = tid & 63;
  const int wv   = tid >> 6;
  const int q    = wv & 3;                 // pair-quarter
  const int g    = wv >> 2;                // row-group
  const int r0   = blockIdx.x * 4 + 2 * g; // rows r0, r0+1
  const bool l0 = (lane == 0), l63 = (lane == 63);
  const bool q0 = (q == 0), q3 = (q == 3);

  // state: elem e <-> pair p = 256q + 4*lane + e; reg at step T: F:(e-T)&3, S:(e+T)&3
  f32x2 FF[4], SS[4];
#pragma unroll
  for (int e = 0; e < 4; ++e) {
    const int p = 256 * q + 4 * lane + e;
    FF[e] = (f32x2){(p == r0) ? 1.f : 0.f, (p == r0 + 1) ? 1.f : 0.f};
    SS[e] = (f32x2){((2047 - p) == r0) ? 1.f : 0.f, ((2047 - p) == r0 + 1) ? 1.f : 0.f};
  }

  // swizzled cv read offsets (2 x float4 = 32B per lane per step); A = a ^ (16*((a>>7)&7))
  const unsigned swz = 16u * (((unsigned)lane >> 2) & 7u);
  const unsigned aoff0 = (2048u * q + 32u * (unsigned)lane) ^ swz;
  const unsigned aoff1 = (2048u * q + 32u * (unsigned)lane + 16u) ^ swz;

  // staging: wave wv stages 1KB block wv; linear LDS dest d = 1024*wv + 16*lane,
  // pre-swizzled global source = d ^ ((d>>3)&0x70)  (same involution as read side)
  const unsigned d0 = 1024u * (unsigned)wv + 16u * (unsigned)lane;
  const char* gp = csb + (d0 ^ ((d0 >> 3) & 0x70u));

  // prologue: stage slices 0,1,2 into bufs 0,1,2
#pragma unroll
  for (int s = 0; s < 3; ++s) {
    gload_lds16(gp, &lds_cs[s][1024 * wv]);
    gp += 8192;
  }
  asm volatile("s_waitcnt vmcnt(2)" ::: "memory");   // slice 0 landed (1,2 in flight)
  __builtin_amdgcn_s_barrier();
  __builtin_amdgcn_sched_barrier(0);

#define ROT1(E, CC, SV) { \
    const int rF = ((E) - PHI) & 3, rS = ((E) + PHI) & 3; \
    const f32x2 c2 = {CC, CC}, s2 = {SV, SV}; \
    const f32x2 vi = FF[rF], vj = SS[rS]; \
    FF[rF] = c2 * vi + s2 * vj; \
    SS[rS] = c2 * vj - s2 * vi; }

#define STEP(PHI_) { \
    const int PHI = (PHI_); \
    const int PAR = PHI & 1; \
    const int pF = (3 - PHI) & 3, pT = (4 - PHI) & 3; \
    const float4 cv0 = *(const float4*)&lds_cs[PHI][aoff0]; \
    const float4 cv1 = *(const float4*)&lds_cs[PHI][aoff1]; \
    ROT1(0, cv0.x, cv0.y) ROT1(1, cv0.z, cv0.w) \
    ROT1(2, cv1.x, cv1.y) ROT1(3, cv1.z, cv1.w) \
    const f32x2 Fo = FF[pF], So = SS[PHI], St = FF[pT]; \
    f32x2 fi, sd; \
    fi.x = __shfl_up(Fo.x, 1);   fi.y = __shfl_up(Fo.y, 1); \
    sd.x = __shfl_down(So.x, 1); sd.y = __shfl_down(So.y, 1); \
    if (!q3 && l63) exch[PAR][g][0][q]     = Fo; \
    if (!q0 && l0)  exch[PAR][g][1][q - 1] = So; \
    gload_lds16(gp, &lds_cs[(PHI + 3) & 3][1024 * wv]); \
    gp += 8192; \
    asm volatile("s_waitcnt vmcnt(2) lgkmcnt(0)" ::: "memory"); \
    __builtin_amdgcn_s_barrier(); \
    __builtin_amdgcn_sched_barrier(0); \
    f32x2 eF = {0.f, 0.f}, eS = {0.f, 0.f}; \
    if (!q0 && l0)  eF = exch[PAR][g][0][q - 1]; \
    if (!q3 && l63) eS = exch[PAR][g][1][q]; \
    FF[pF]  = l0  ? (q0 ? St : eF) : fi; \
    SS[PHI] = l63 ? (q3 ? Fo : eS) : sd; \
    if (q0) { FF[pT] = l0 ? So : FF[pT]; } \
  }

#pragma unroll 1
  for (int it = 0; it < 511; ++it) {
    STEP(0) STEP(1) STEP(2) STEP(3)
  }
  // tail: t = 2044, 2045, 2046 (stages pad slices 2047-2049, never read)
  STEP(0) STEP(1) STEP(2)

  // Readout at T=2047 (cycle closed; 2047 mod 4 = 3):
  // F elem e in reg (e+1)&3, col 256q+4l+e; S elem e in reg (e-1)&3, col 2047-(256q+4l+e)
  const int cf  = 256 * q + 4 * lane;
  const int cs_ = 2044 - cf;
#pragma unroll
  for (int rr = 0; rr < 2; ++rr) {
    unsigned short* rp = Ub + (size_t)(r0 + rr) * NN;
    const float f1 = rr ? FF[1].y : FF[1].x, f2 = rr ? FF[2].y : FF[2].x;
    const float f3 = rr ? FF[3].y : FF[3].x, f0 = rr ? FF[0].y : FF[0].x;
    const float s2 = rr ? SS[2].y : SS[2].x, s1 = rr ? SS[1].y : SS[1].x;
    const float s0 = rr ? SS[0].y : SS[0].x, s3 = rr ? SS[3].y : SS[3].x;
    const unsigned uf0 = (unsigned)f2bf(f1) | ((unsigned)f2bf(f2) << 16);
    const unsigned uf1 = (unsigned)f2bf(f3) | ((unsigned)f2bf(f0) << 16);
    const unsigned us0 = (unsigned)f2bf(s2) | ((unsigned)f2bf(s1) << 16);
    const unsigned us1 = (unsigned)f2bf(s0) | ((unsigned)f2bf(s3) << 16);
    *(uint2*)(rp + cf)  = make_uint2(uf0, uf1);
    *(uint2*)(rp + cs_) = make_uint2(us0, us1);
  }
}

// ---- kernel 4: C = A * B^T + bias.  A = x_bf16 [8192][2048], B = U_bf16 [2048][2048]
#define BM 128
#define BN 128
#define BK 32

__global__ __launch_bounds__(256) void gemm_kernel(
    const unsigned short* __restrict__ A, const unsigned short* __restrict__ B,
    const float* __restrict__ bias, float* __restrict__ C) {
  __shared__ unsigned short As[BM * BK];
  __shared__ unsigned short Bs[BN * BK];
  const int tid  = threadIdx.x;
  const int lane = tid & 63;
  const int wave = tid >> 6;
  const int bm = blockIdx.x, bn = blockIdx.y;
  const int wm = wave & 1, wn = wave >> 1;

  const int srow = wave * 16 + (lane >> 2);
  const int scol = (lane & 3) * 8;
  const unsigned short* Ag = A + (size_t)(bm * BM + srow) * NN + scol;
  const unsigned short* Bg = B + (size_t)(bn * BN + srow) * NN + scol;

  const int fm = lane & 15;
  const int kb = lane >> 4;

  f32x4 acc[4][4];
#pragma unroll
  for (int a_ = 0; a_ < 4; ++a_)
#pragma unroll
    for (int b_ = 0; b_ < 4; ++b_) acc[a_][b_] = (f32x4){0.f, 0.f, 0.f, 0.f};

  for (int kt = 0; kt < NN / BK; ++kt) {
    const int k0 = kt * BK;
#pragma unroll
    for (int it = 0; it < 2; ++it) {
      gload_lds16(Ag + (size_t)(it * 64) * NN + k0, &As[wave * 512 + it * 2048]);
      gload_lds16(Bg + (size_t)(it * 64) * NN + k0, &Bs[wave * 512 + it * 2048]);
    }
    __syncthreads();

    bf16x8 af[4], bfr[4];
#pragma unroll
    for (int a_ = 0; a_ < 4; ++a_)
      af[a_] = *(const bf16x8*)&As[(wm * 64 + a_ * 16 + fm) * BK + kb * 8];
#pragma unroll
    for (int b_ = 0; b_ < 4; ++b_)
      bfr[b_] = *(const bf16x8*)&Bs[(wn * 64 + b_ * 16 + fm) * BK + kb * 8];
#pragma unroll
    for (int a_ = 0; a_ < 4; ++a_)
#pragma unroll
      for (int b_ = 0; b_ < 4; ++b_)
        acc[a_][b_] = __builtin_amdgcn_mfma_f32_16x16x32_bf16(af[a_], bfr[b_], acc[a_][b_], 0, 0, 0);
    __syncthreads();
  }

  const int row_in = (lane >> 4) * 4;
#pragma unroll
  for (int a_ = 0; a_ < 4; ++a_) {
#pragma unroll
    for (int b_ = 0; b_ < 4; ++b_) {
      int gn = bn * BN + wn * 64 + b_ * 16 + fm;
      float bv = bias[gn];
#pragma unroll
      for (int v = 0; v < 4; ++v) {
        int gm = bm * BM + wm * 64 + a_ * 16 + row_in + v;
        C[(size_t)gm * NN + gn] = acc[a_][b_][v] + bv;
      }
    }
  }
}

extern "C" void kernel_launch(void* const* d_in, const int* in_sizes, int n_in,
                              void* d_out, int out_size, void* d_ws, size_t ws_size,
                              hipStream_t stream) {
  const float* x      = (const float*)d_in[0];
  const float* angles = (const float*)d_in[1];
  const float* bias   = (const float*)d_in[2];
  float* out = (float*)d_out;

  char* ws = (char*)d_ws;
  char*           cs = ws;                                 // 2052 slices * 8KB = 16,809,984 B (2047 real + pad)
  unsigned short* xb = (unsigned short*)(ws + 16809984);   // 33,554,432 B
  unsigned short* Ub = (unsigned short*)(ws + 50364416);   //  8,388,608 B
  // total 58,753,024 B

  prep_kernel<<<dim3(8188), dim3(256), 0, stream>>>(angles, (float2*)cs);
  cvt_kernel<<<dim3(16384), dim3(256), 0, stream>>>((const float4*)x, (ushort4*)xb,
                                                    MROWS * NN / 4);
  build_kernel<<<dim3(512), dim3(512), 0, stream>>>(cs, Ub);
  gemm_kernel<<<dim3(MROWS / BM, NN / BN), dim3(256), 0, stream>>>(xb, Ub, bias, out);
}

// Round 6
// 1177.654 us; speedup vs baseline: 1.0670x; 1.0670x over previous
//
#include <hip/hip_runtime.h>
#include <hip/hip_bf16.h>

#define NN      2048
#define NSTEPS  2047
#define NPAIRS  1024
#define MROWS   8192

typedef __attribute__((ext_vector_type(8))) __bf16 bf16x8;
typedef __attribute__((ext_vector_type(4))) float  f32x4;
typedef __attribute__((ext_vector_type(2))) float  f32x2;

__device__ __forceinline__ unsigned short f2bf(float f) {
  unsigned int u = __float_as_uint(f);
  u += 0x7fffu + ((u >> 16) & 1u);   // RNE
  return (unsigned short)(u >> 16);
}

__device__ __forceinline__ void gload_lds16(const void* g, void* l) {
  __builtin_amdgcn_global_load_lds((const __attribute__((address_space(1))) void*)g,
                                   (__attribute__((address_space(3))) void*)l, 16, 0, 0);
}

// DPP wave-wide lane shifts (VALU pipe, no LDS). gfx9-lineage ctrl codes:
// wave_shr1 = 0x138: dst[i] = src[i-1]  (shfl_up 1)
// wave_shl1 = 0x130: dst[i] = src[i+1]  (shfl_down 1)
template<int CTRL>
__device__ __forceinline__ float dppf(float v) {
  return __int_as_float(__builtin_amdgcn_update_dpp(
      __float_as_int(v), __float_as_int(v), CTRL, 0xf, 0xf, false));
}
#define DPP_UP 0x138
#define DPP_DN 0x130

// ---- kernel 1: angles -> (cos,sin) table, layout cs[step][pair] (8 KB/step slice)
__global__ __launch_bounds__(256) void prep_kernel(
    const float* __restrict__ angles, float2* __restrict__ cs) {
  int idx = blockIdx.x * 256 + threadIdx.x;
  if (idx >= NSTEPS * NPAIRS) return;
  float s, c;
  sincosf(angles[idx], &s, &c);
  cs[idx] = make_float2(c, s);
}

// ---- kernel 2: x fp32 -> bf16 (vectorized)
__global__ __launch_bounds__(256) void cvt_kernel(
    const float4* __restrict__ x, ushort4* __restrict__ xb, int n4) {
  int idx = blockIdx.x * 256 + threadIdx.x;
  if (idx >= n4) return;
  float4 v = x[idx];
  ushort4 o;
  o.x = f2bf(v.x); o.y = f2bf(v.y); o.z = f2bf(v.z); o.w = f2bf(v.w);
  xb[idx] = o;
}

// ---- kernel 3: register-systolic build of U (position space, static pairing).
// WG = 8 waves (512 thr), one per pair-octant q=0..7; WG owns 4 rows (r0..r0+3):
// A = rows 0-1, B = rows 2-3 as f32x2. Lane of octant q owns pairs p0=128q+2l, p0+1.
// Reg mapping at step T (PHI=T&1): F elem e <-> reg[(e-T)&1], S elem e <-> reg[(e+T)&1]
//   => e0 in reg[PHI], e1 in reg[PHI^1] for BOTH F and S.
// Shifts: intra-wave via DPP (VALU pipe); inter-wave via tiny LDS exch (parity dbuf).
// cs: direct global->reg float4 per lane per step, double-buffered 2 slices ahead.
__global__ __launch_bounds__(512, 4) void build_kernel(
    const char* __restrict__ csb, unsigned short* __restrict__ Ub) {
  __shared__ float4 exF[2][7], exS[2][7];

  const int tid  = threadIdx.x;
  const int lane = tid & 63;
  const int q    = tid >> 6;
  const int r0   = blockIdx.x * 4;
  const bool l0 = (lane == 0), l63 = (lane == 63);
  const bool q0 = (q == 0), q7 = (q == 7);
  const int p0 = 128 * q + 2 * lane;

  f32x2 FA[2], FB[2], SA[2], SB[2];
#pragma unroll
  for (int e = 0; e < 2; ++e) {
    const int p = p0 + e, m = 2047 - p;
    FA[e] = (f32x2){(p == r0) ? 1.f : 0.f, (p == r0 + 1) ? 1.f : 0.f};
    FB[e] = (f32x2){(p == r0 + 2) ? 1.f : 0.f, (p == r0 + 3) ? 1.f : 0.f};
    SA[e] = (f32x2){(m == r0) ? 1.f : 0.f, (m == r0 + 1) ? 1.f : 0.f};
    SB[e] = (f32x2){(m == r0 + 2) ? 1.f : 0.f, (m == r0 + 3) ? 1.f : 0.f};
  }

  const char* gpA = csb + 1024 * q + 16 * lane;   // even slices
  const char* gpB = gpA + 8192;                   // odd slices
  float4 cvA = *(const float4*)gpA;               // slice 0
  float4 cvB = *(const float4*)gpB;               // slice 1
  gpA += 16384; gpB += 16384;                     // -> slices 2, 3

#define STEP(PHI, CV, GP) { \
    { const f32x2 c0 = {CV.x, CV.x}, s0 = {CV.y, CV.y}; \
      f32x2 vi, vj; \
      vi = FA[PHI]; vj = SA[PHI]; FA[PHI] = c0*vi + s0*vj; SA[PHI] = c0*vj - s0*vi; \
      vi = FB[PHI]; vj = SB[PHI]; FB[PHI] = c0*vi + s0*vj; SB[PHI] = c0*vj - s0*vi; \
      const f32x2 c1 = {CV.z, CV.z}, s1 = {CV.w, CV.w}; \
      vi = FA[PHI^1]; vj = SA[PHI^1]; FA[PHI^1] = c1*vi + s1*vj; SA[PHI^1] = c1*vj - s1*vi; \
      vi = FB[PHI^1]; vj = SB[PHI^1]; FB[PHI^1] = c1*vi + s1*vj; SB[PHI^1] = c1*vj - s1*vi; } \
    const f32x2 FoA = FA[PHI^1], FoB = FB[PHI^1];   /* departing elem1 (F top) */ \
    const f32x2 SoA = SA[PHI],   SoB = SB[PHI];     /* departing elem0 (S bottom) */ \
    const f32x2 StA = FA[PHI],   StB = FB[PHI];     /* elem0 (pos-0 stationary) */ \
    f32x2 fiA, fiB, sdA, sdB; \
    fiA.x = dppf<DPP_UP>(FoA.x); fiA.y = dppf<DPP_UP>(FoA.y); \
    fiB.x = dppf<DPP_UP>(FoB.x); fiB.y = dppf<DPP_UP>(FoB.y); \
    sdA.x = dppf<DPP_DN>(SoA.x); sdA.y = dppf<DPP_DN>(SoA.y); \
    sdB.x = dppf<DPP_DN>(SoB.x); sdB.y = dppf<DPP_DN>(SoB.y); \
    if (!q7 && l63) exF[PHI][q]     = make_float4(FoA.x, FoA.y, FoB.x, FoB.y); \
    if (!q0 && l0)  exS[PHI][q - 1] = make_float4(SoA.x, SoA.y, SoB.x, SoB.y); \
    CV = *(const float4*)GP; GP += 16384;           /* prefetch slice t+2 */ \
    asm volatile("s_waitcnt lgkmcnt(0)" ::: "memory"); \
    __builtin_amdgcn_s_barrier(); \
    __builtin_amdgcn_sched_barrier(0); \
    float4 eF = make_float4(0.f, 0.f, 0.f, 0.f), eS = eF; \
    if (!q0 && l0)  eF = exF[PHI][q - 1]; \
    if (!q7 && l63) eS = exS[PHI][q]; \
    FA[PHI^1] = l0  ? (q0 ? StA : (f32x2){eF.x, eF.y}) : fiA;   /* new elem0 */ \
    FB[PHI^1] = l0  ? (q0 ? StB : (f32x2){eF.z, eF.w}) : fiB; \
    SA[PHI]   = l63 ? (q7 ? FoA : (f32x2){eS.x, eS.y}) : sdA;   /* new elem1 */ \
    SB[PHI]   = l63 ? (q7 ? FoB : (f32x2){eS.z, eS.w}) : sdB; \
    if (q0) { FA[PHI] = l0 ? SoA : FA[PHI];                     /* pos2047 -> pos1 */ \
              FB[PHI] = l0 ? SoB : FB[PHI]; } \
  }

#pragma unroll 1
  for (int it = 0; it < 1023; ++it) {
    STEP(0, cvA, gpA)
    STEP(1, cvB, gpB)
  }
  // tail: t = 2046 (prefetch reads pad slice 2048, never consumed)
  STEP(0, cvA, gpA)

  // Readout at T=2047: F elem e in reg[(e+1)&1]; S elem e in reg[(e+1)&1].
  // F elem e -> col p0+e; S elem e -> col 2047-(p0+e).
#pragma unroll
  for (int rr = 0; rr < 4; ++rr) {
    unsigned short* rp = Ub + (size_t)(r0 + rr) * NN;
    const f32x2* Fr = (rr < 2) ? FA : FB;
    const f32x2* Sr = (rr < 2) ? SA : SB;
    const bool hi = (rr & 1);
    const float f0 = hi ? Fr[1].y : Fr[1].x;   // F elem0
    const float f1 = hi ? Fr[0].y : Fr[0].x;   // F elem1
    const float s0 = hi ? Sr[1].y : Sr[1].x;   // S elem0 -> col 2047-p0
    const float s1 = hi ? Sr[0].y : Sr[0].x;   // S elem1 -> col 2046-p0
    *(unsigned*)(rp + p0)          = (unsigned)f2bf(f0) | ((unsigned)f2bf(f1) << 16);
    *(unsigned*)(rp + (2046 - p0)) = (unsigned)f2bf(s1) | ((unsigned)f2bf(s0) << 16);
  }
}

// ---- kernel 4: C = A * B^T + bias.  A = x_bf16 [8192][2048], B = U_bf16 [2048][2048]
#define BM 128
#define BN 128
#define BK 32

__global__ __launch_bounds__(256) void gemm_kernel(
    const unsigned short* __restrict__ A, const unsigned short* __restrict__ B,
    const float* __restrict__ bias, float* __restrict__ C) {
  __shared__ unsigned short As[BM * BK];
  __shared__ unsigned short Bs[BN * BK];
  const int tid  = threadIdx.x;
  const int lane = tid & 63;
  const int wave = tid >> 6;
  const int bm = blockIdx.x, bn = blockIdx.y;
  const int wm = wave & 1, wn = wave >> 1;

  const int srow = wave * 16 + (lane >> 2);
  const int scol = (lane & 3) * 8;
  const unsigned short* Ag = A + (size_t)(bm * BM + srow) * NN + scol;
  const unsigned short* Bg = B + (size_t)(bn * BN + srow) * NN + scol;

  const int fm = lane & 15;
  const int kb = lane >> 4;

  f32x4 acc[4][4];
#pragma unroll
  for (int a_ = 0; a_ < 4; ++a_)
#pragma unroll
    for (int b_ = 0; b_ < 4; ++b_) acc[a_][b_] = (f32x4){0.f, 0.f, 0.f, 0.f};

  for (int kt = 0; kt < NN / BK; ++kt) {
    const int k0 = kt * BK;
#pragma unroll
    for (int it = 0; it < 2; ++it) {
      gload_lds16(Ag + (size_t)(it * 64) * NN + k0, &As[wave * 512 + it * 2048]);
      gload_lds16(Bg + (size_t)(it * 64) * NN + k0, &Bs[wave * 512 + it * 2048]);
    }
    __syncthreads();

    bf16x8 af[4], bfr[4];
#pragma unroll
    for (int a_ = 0; a_ < 4; ++a_)
      af[a_] = *(const bf16x8*)&As[(wm * 64 + a_ * 16 + fm) * BK + kb * 8];
#pragma unroll
    for (int b_ = 0; b_ < 4; ++b_)
      bfr[b_] = *(const bf16x8*)&Bs[(wn * 64 + b_ * 16 + fm) * BK + kb * 8];
#pragma unroll
    for (int a_ = 0; a_ < 4; ++a_)
#pragma unroll
      for (int b_ = 0; b_ < 4; ++b_)
        acc[a_][b_] = __builtin_amdgcn_mfma_f32_16x16x32_bf16(af[a_], bfr[b_], acc[a_][b_], 0, 0, 0);
    __syncthreads();
  }

  const int row_in = (lane >> 4) * 4;
#pragma unroll
  for (int a_ = 0; a_ < 4; ++a_) {
#pragma unroll
    for (int b_ = 0; b_ < 4; ++b_) {
      int gn = bn * BN + wn * 64 + b_ * 16 + fm;
      float bv = bias[gn];
#pragma unroll
      for (int v = 0; v < 4; ++v) {
        int gm = bm * BM + wm * 64 + a_ * 16 + row_in + v;
        C[(size_t)gm * NN + gn] = acc[a_][b_][v] + bv;
      }
    }
  }
}

extern "C" void kernel_launch(void* const* d_in, const int* in_sizes, int n_in,
                              void* d_out, int out_size, void* d_ws, size_t ws_size,
                              hipStream_t stream) {
  const float* x      = (const float*)d_in[0];
  const float* angles = (const float*)d_in[1];
  const float* bias   = (const float*)d_in[2];
  float* out = (float*)d_out;

  char* ws = (char*)d_ws;
  char*           cs = ws;                                 // 2049 slices * 8KB = 16,785,408 B (2047 real + 2 pad)
  unsigned short* xb = (unsigned short*)(ws + 16785408);   // 33,554,432 B
  unsigned short* Ub = (unsigned short*)(ws + 50339840);   //  8,388,608 B
  // total 58,728,448 B

  prep_kernel<<<dim3(8188), dim3(256), 0, stream>>>(angles, (float2*)cs);
  cvt_kernel<<<dim3(16384), dim3(256), 0, stream>>>((const float4*)x, (ushort4*)xb,
                                                    MROWS * NN / 4);
  build_kernel<<<dim3(512), dim3(512), 0, stream>>>(cs, Ub);
  gemm_kernel<<<dim3(MROWS / BM, NN / BN), dim3(256), 0, stream>>>(xb, Ub, bias, out);
}